// Round 16
// baseline (276.975 us; speedup 1.0000x reference)
//
#include <hip/hip_runtime.h>
#include <hip/hip_bf16.h>
#include <stdint.h>

// HierarchicalAttention: B=4 S=8192 D=512 H=8 DK=64 LOCAL_W=256 STRIDE=64
// Baseline r15: 275.5us. Dead ends documented:
//  - GEMM same-region schedules: 6 variants, all 24-28% MfmaUtil. This round
//    tries CROSS-REGION decoupling (prefetch frags one barrier early).
//  - (512,4) bounds -> acc spills (r7). LN-fusion (r9), SEC-fold (r11),
//    attn QBLK=128 (r14): all regressions, reverted.
#define B_ 4
#define S_ 8192
#define D_ 512
#define H_ 8
#define DK_ 64
#define G_ 128
#define ROWS_ (B_*S_)   // 32768

typedef unsigned short u16;
typedef __attribute__((ext_vector_type(8))) short short8;   // 8 x bf16 (4 VGPR)
typedef __attribute__((ext_vector_type(4))) short short4v;  // 4 x bf16
typedef __attribute__((ext_vector_type(4))) float floatx4;

static __device__ __forceinline__ float bf2f(u16 u){
  union { uint32_t i; float f; } v; v.i = ((uint32_t)u) << 16; return v.f;
}
static __device__ __forceinline__ u16 f2bf(float f){
  union { float f; uint32_t i; } v; v.f = f;
  uint32_t u = v.i; u += 0x7fff + ((u >> 16) & 1); return (u16)(u >> 16);
}

// async global->LDS, 16B per lane. LDS dest must be wave-uniform base; HW
// writes lane l at ldsbase + l*16 (m104). Global src is per-lane.
static __device__ __forceinline__ void glds16(const u16* g, u16* l){
  __builtin_amdgcn_global_load_lds(
      (const __attribute__((address_space(1))) void*)g,
      (__attribute__((address_space(3))) void*)l, 16, 0, 0);
}

// ---------------- cast x (fp32 -> bf16) + gather global tokens ----------------
__global__ void cast_x_kernel(const float* __restrict__ x, u16* __restrict__ xb,
                              u16* __restrict__ xg, int n4){
  int i = blockIdx.x*blockDim.x + threadIdx.x;
  if (i >= n4) return;
  float4 v = ((const float4*)x)[i];
  short4v o;
  o[0] = (short)f2bf(v.x); o[1] = (short)f2bf(v.y);
  o[2] = (short)f2bf(v.z); o[3] = (short)f2bf(v.w);
  *(short4v*)(xb + (size_t)i*4) = o;
  int row = i >> 7;                      // token row (D=512, 4 elems/thread)
  if ((row & 63) == 0){                  // every 64th token -> xg
    int b = row >> 13, g = (row & 8191) >> 6;
    *(short4v*)(xg + ((size_t)(b*G_ + g)*D_) + (i & 127)*4) = o;
  }
}

// ---------------- transpose+cast weight: W (K x N) f32 -> Ot (N x K) bf16 ----------------
__global__ void transpose_cast_kernel(const float* __restrict__ W, u16* __restrict__ Ot, int K, int N){
  __shared__ float t[64][65];
  int n0 = blockIdx.x*64, k0 = blockIdx.y*64;
  int tx = threadIdx.x & 63, ty = threadIdx.x >> 6; // ty 0..3
#pragma unroll
  for (int j=0;j<16;j++){ int k = ty + j*4; t[k][tx] = W[(size_t)(k0+k)*N + n0+tx]; }
  __syncthreads();
#pragma unroll
  for (int j=0;j<16;j++){ int n = ty + j*4; Ot[(size_t)(n0+n)*K + k0 + tx] = f2bf(t[tx][n]); }
}

// six 512x512 transposes in one launch (z selects source)
__global__ void transpose_cast6_kernel(const float* s0, const float* s1, const float* s2,
    const float* s3, const float* s4, const float* s5,
    u16* __restrict__ WcatT, u16* __restrict__ WgT){
  __shared__ float t[64][65];
  int z = blockIdx.z;
  const float* W = (z==0)?s0:(z==1)?s1:(z==2)?s2:(z==3)?s3:(z==4)?s4:s5;
  u16* Ot = (z<4) ? (WcatT + (size_t)z*512*512) : (WgT + (size_t)(z-4)*512*512);
  int n0 = blockIdx.x*64, k0 = blockIdx.y*64;
  int tx = threadIdx.x & 63, ty = threadIdx.x >> 6;
#pragma unroll
  for (int j=0;j<16;j++){ int k = ty + j*4; t[k][tx] = W[(size_t)(k0+k)*512 + n0+tx]; }
  __syncthreads();
#pragma unroll
  for (int j=0;j<16;j++){ int n = ty + j*4; Ot[(size_t)(n0+n)*512 + k0 + tx] = f2bf(t[tx][n]); }
}

// ---------------- bias concat ----------------
__global__ void build_bias_kernel(float* __restrict__ bcat, float* __restrict__ bg,
    const float* lq_b, const float* lk_b, const float* lv_b, const float* gq_b,
    const float* gk_b, const float* gv_b){
  int i = blockIdx.x*blockDim.x + threadIdx.x;
  if (i < 2048){
    const float* s = (i < 512) ? lq_b : (i < 1024) ? lk_b : (i < 1536) ? lv_b : gq_b;
    bcat[i] = s[i & 511];
  } else if (i < 3072){
    int j = i - 2048;
    bg[j] = (j < 512) ? gk_b[j] : gv_b[j - 512];
  }
}

// ============ 256x256 BK=32, 4-deep ring, CROSS-REGION prefetch GEMM ============
// Fragment ds_reads for tile t+1 are issued in region t (overlapping tile t's
// MFMAs); MFMA(t) consumes registers read in region t-1. Counted vmcnt(4)
// guarantees tile t+1 resident at barrier_t (t+2,t+3 DMA in flight).
// Ring hazard: reads of tile t complete (lgkm) before barrier_{t+1}; slot's
// next DMA writer (t+4) issues after barrier_{t+1}. One barrier per tile.
// VGPR: 128 acc + 2x48 frags + addr ~ 240 < 256 (1 block/CU, (512,1)).
// REQUIRES: T even, T >= 4. GRID MUST BE MULTIPLE OF 256 BLOCKS.
template<int EPI>
__global__ __launch_bounds__(512, 1) void gemm_big(
    const u16* __restrict__ A, const u16* __restrict__ Bt,
    const float* __restrict__ bias, u16* __restrict__ C,
    const u16* __restrict__ X, int M, int N, int K)
{
  __shared__ u16 SM[4][16384];   // 4 x 32KB: [A 16 frag-blocks | B 16 frag-blocks]
  const int tid = threadIdx.x, lane = tid & 63, w = tid >> 6;
  const int wm = w >> 2, wn = w & 3;          // 2M x 4N waves
  const int gx = gridDim.x;
  const int h = blockIdx.y * gx + blockIdx.x;
  const int chunk = (gx * gridDim.y) >> 3;
  const int work = (h & 7) * chunk + (h >> 3);   // XCD-aware bijective remap
  const int bx = work % gx, by = work / gx;
  const int m0 = by*256, n0 = bx*256;
  const int T = K >> 5;          // BK=32 tiles (even)

  const u16* gsrc[4]; int loff[4];
#pragma unroll
  for (int j = 0; j < 4; j++){
    int fb  = w*4 + j;
    int isB = fb >> 4;
    int blk = fb & 15;
    const u16* bp = isB ? Bt : A;
    int row = (isB ? n0 : m0) + blk*16 + (lane & 15);
    gsrc[j] = bp + (size_t)row * K + ((lane >> 4) * 8);
    loff[j] = fb*512;
  }

  floatx4 acc[8][4] = {};

  auto stageT = [&](int tt){
    u16* Sb_ = &SM[tt & 3][0];
#pragma unroll
    for (int j = 0; j < 4; j++) glds16(gsrc[j] + tt*32, Sb_ + loff[j]);
  };
  auto readFrags = [&](short8* Sa, short8* Sb, int slot){
    const u16* Tb = &SM[slot][0];
#pragma unroll
    for (int i=0;i<8;i++) Sa[i] = *(const short8*)(Tb + (wm*8 + i)*512 + lane*8);
#pragma unroll
    for (int j=0;j<4;j++) Sb[j] = *(const short8*)(Tb + (16 + wn*4 + j)*512 + lane*8);
  };
  auto doMfma = [&](const short8* Sa, const short8* Sb){
#pragma unroll
    for (int i=0;i<8;i++)
#pragma unroll
      for (int j=0;j<4;j++)
        acc[i][j] = __builtin_amdgcn_mfma_f32_16x16x32_bf16(Sa[i], Sb[j], acc[i][j], 0,0,0);
  };

  short8 A0[8], B0[4], A1[8], B1[4];

  // ---- prologue: stage tiles 0,1,2; read tile-0 fragments ----
  stageT(0); stageT(1); stageT(2);
  asm volatile("s_waitcnt vmcnt(8)" ::: "memory");   // tile 0 resident
  __builtin_amdgcn_s_barrier();
  readFrags(A0, B0, 0);

  for (int t = 0; t < T; t += 2){
    // ---- even region: consume tile t (A0,B0), prefetch tile t+1 (A1,B1) ----
    if (t + 2 < T) asm volatile("s_waitcnt vmcnt(4)" ::: "memory");  // t+1 resident
    else           asm volatile("s_waitcnt vmcnt(0)" ::: "memory");
    __builtin_amdgcn_s_barrier();
    if (t + 3 < T) stageT(t + 3);
    readFrags(A1, B1, (t + 1) & 3);
    doMfma(A0, B0);

    // ---- odd region: consume tile t+1, prefetch tile t+2 ----
    if (t + 3 < T) asm volatile("s_waitcnt vmcnt(4)" ::: "memory");  // t+2 resident
    else           asm volatile("s_waitcnt vmcnt(0)" ::: "memory");
    __builtin_amdgcn_s_barrier();
    if (t + 4 < T) stageT(t + 4);
    if (t + 2 < T) readFrags(A0, B0, (t + 2) & 3);
    doMfma(A1, B1);
  }

  // ---- epilogue ----
#pragma unroll
  for (int mi=0; mi<8; mi++)
#pragma unroll
    for (int nj=0; nj<4; nj++){
      int col = n0 + (wn*4 + nj)*16 + (lane & 15);
      float bv = bias[col];
#pragma unroll
      for (int ii=0; ii<4; ii++){
        size_t row = (size_t)(m0 + (wm*8 + mi)*16 + (lane>>4)*4 + ii);
        float v = acc[mi][nj][ii] + bv;
        if (EPI == 1) v += bf2f(X[row*N + col]);
        C[row*N + col] = f2bf(v);
      }
    }
}

// ---------------- small 128^2 GEMM (for 512x1024x512 gkv) ----------------
__global__ __launch_bounds__(256) void gemm_small(
    const u16* __restrict__ A, const u16* __restrict__ Bt,
    const float* __restrict__ bias, u16* __restrict__ C,
    int M, int N, int K)
{
  __shared__ u16 As[128*32];
  __shared__ u16 Bs[128*32];
  const int tid = threadIdx.x, lane = tid & 63, w = tid >> 6;
  const int m0 = blockIdx.y*128, n0 = blockIdx.x*128;
  const int wm = (w>>1)*64, wn = (w&1)*64;
  floatx4 acc[4][4] = {};
  const int c0 = 2*w;
  const int sr = lane >> 2;
  const int sc = (lane & 3) * 8;
  const u16* ga0 = A  + (size_t)(m0 +  c0     *16 + sr)*K + sc;
  const u16* ga1 = A  + (size_t)(m0 + (c0 + 1)*16 + sr)*K + sc;
  const u16* gb0 = Bt + (size_t)(n0 +  c0     *16 + sr)*K + sc;
  const u16* gb1 = Bt + (size_t)(n0 + (c0 + 1)*16 + sr)*K + sc;
  u16* la0 = &As[ c0     *512];
  u16* la1 = &As[(c0 + 1)*512];
  u16* lb0 = &Bs[ c0     *512];
  u16* lb1 = &Bs[(c0 + 1)*512];

  for (int k0 = 0; k0 < K; k0 += 32){
    __syncthreads();
    glds16(ga0 + k0, la0);
    glds16(ga1 + k0, la1);
    glds16(gb0 + k0, lb0);
    glds16(gb1 + k0, lb1);
    __syncthreads();
    short8 af[4], bf[4];
#pragma unroll
    for (int i=0;i<4;i++) af[i] = *(const short8*)&As[(wm + i*16 + (lane&15))*32 + (lane>>4)*8];
#pragma unroll
    for (int i=0;i<4;i++) bf[i] = *(const short8*)&Bs[(wn + i*16 + (lane&15))*32 + (lane>>4)*8];
#pragma unroll
    for (int mi=0;mi<4;mi++)
#pragma unroll
      for (int ni=0;ni<4;ni++)
        acc[mi][ni] = __builtin_amdgcn_mfma_f32_16x16x32_bf16(af[mi], bf[ni], acc[mi][ni], 0,0,0);
  }

#pragma unroll
  for (int mi=0;mi<4;mi++)
#pragma unroll
    for (int ni=0;ni<4;ni++){
      int col = n0 + wn + ni*16 + (lane&15);
      float bv = bias[col];
#pragma unroll
      for (int i=0;i<4;i++){
        size_t row = (size_t)(m0 + wm + mi*16 + (lane>>4)*4 + i);
        C[row*N + col] = f2bf(acc[mi][ni][i] + bv);
      }
    }
}

// ================= attention (r12 proven form) =================
// 512 threads (8 waves), per block: one (b, window, head): 256 q-rows.
// K staged ONCE to LDS via glds16 with pre-swizzled SOURCE (rule 21);
// V transposed via all-thread 4x8 in-register transpose + swizzled ds_write_b64;
// P per-wave swizzled LDS strip; no barriers in the strip loop.
// Softmax WITHOUT max-subtraction (scores ~N(0,1): exact, overflow-safe).
template<int KVLEN, int KSTRIDE, bool GLOBAL>
__global__ __launch_bounds__(512, 2) void attn_kernel(
    const u16* __restrict__ qkv, const u16* __restrict__ kvbuf, u16* __restrict__ comb)
{
  __shared__ u16 SM[KVLEN*256];
  u16* Kl = SM;                       // [row][64] swizzled chunks
  u16* Vt = SM + KVLEN*64;            // [d=64][KVLEN] swizzled chunks
  u16* Pl = SM + KVLEN*128;           // [wave][16][KVLEN] swizzled chunks
  const int tid = threadIdx.x, lane = tid & 63, w = tid >> 6;
  const int h = blockIdx.x, n = blockIdx.y, b = blockIdx.z;
  const size_t qrow0 = (size_t)b*S_ + (size_t)n*256;
  const int krow0 = GLOBAL ? b*G_ : (b*S_ + n*256);
  const int qc = (GLOBAL ? 1536 : 0)   + h*DK_;
  const int kc = (GLOBAL ? 0    : 512) + h*DK_;
  const int vc = (GLOBAL ? 512  : 1024)+ h*DK_;
  const int oc = (GLOBAL ? 512  : 0)   + h*DK_;
  constexpr int NF = KVLEN/16;

  // ---- stage K: wave w covers rows [w*KVLEN/8, +KVLEN/8) ----
  {
    const int rpw = KVLEN/8;
    const int r0w = w * rpw;
    const int cg = ((lane & 7) ^ (lane >> 3)) * 8;   // pre-swizzled source chunk
    const int rl = lane >> 3;
#pragma unroll
    for (int j = 0; j < rpw; j += 8){
      int row = r0w + j + rl;
      glds16(kvbuf + (size_t)(krow0 + row)*KSTRIDE + kc + cg, &Kl[(r0w + j)*64]);
    }
  }
  // ---- stage Vt: (KVLEN/4)*8 tasks over ALL threads; 4x8 in-reg transpose ----
  if (tid < (KVLEN/4)*8){
    const int rb = tid >> 3;             // 4-row kv block
    const int kv0 = rb * 4;
    const int d0 = (tid & 7) * 8;
    const u16* vp = kvbuf + (size_t)(krow0 + kv0)*KSTRIDE + vc + d0;
    short8 rIn[4];
#pragma unroll
    for (int i=0;i<4;i++) rIn[i] = *(const short8*)(vp + (size_t)i*KSTRIDE);
    const int c   = rb >> 1;             // kv chunk (8 elems)
    const int sub = kv0 & 7;             // 0 or 4 within chunk
#pragma unroll
    for (int dd=0; dd<8; dd++){
      int d = d0 + dd;
      short4v o;
#pragma unroll
      for (int j=0;j<4;j++) o[j] = rIn[j][dd];
      *(short4v*)&Vt[d*KVLEN + ((c ^ (d&7)) << 3) + sub] = o;
    }
  }
  __syncthreads();

  const float sc2 = 0.125f * 1.44269504f;   // scale * log2(e), for exp2
  const int Pbase = w*16*KVLEN;

  for (int sp = 2*w; sp < 2*w + 2; sp++){
    const u16* qp = qkv + (qrow0 + sp*16 + (lane&15))*2048 + qc + ((lane>>4)*8);
    short8 qf0 = *(const short8*)qp;
    short8 qf1 = *(const short8*)(qp + 32);

    // S = Q K^T  (K from swizzled LDS)
    floatx4 sacc[NF];
#pragma unroll
    for (int nf = 0; nf < NF; nf++){
      const u16* kb = &Kl[(nf*16 + (lane&15))*64];
      short8 kf0 = *(const short8*)(kb + ((( lane>>4)      ^ (lane&7)) << 3));
      short8 kf1 = *(const short8*)(kb + ((((lane>>4) + 4) ^ (lane&7)) << 3));
      floatx4 z = {0.f,0.f,0.f,0.f};
      z = __builtin_amdgcn_mfma_f32_16x16x32_bf16(qf0, kf0, z, 0,0,0);
      z = __builtin_amdgcn_mfma_f32_16x16x32_bf16(qf1, kf1, z, 0,0,0);
      sacc[nf] = z;
    }

    // softmax across KV (no max-shift; scores are O(1))
    float sm[4] = {0.f,0.f,0.f,0.f};
#pragma unroll
    for (int nf=0;nf<NF;nf++)
#pragma unroll
      for (int i=0;i<4;i++){
        float e = exp2f(sacc[nf][i] * sc2);
        sacc[nf][i] = e; sm[i] += e;
      }
#pragma unroll
    for (int i=0;i<4;i++){
#pragma unroll
      for (int msk=1; msk<16; msk<<=1) sm[i] += __shfl_xor(sm[i], msk);
      sm[i] = 1.f / sm[i];
    }

    // write P (bf16) to this wave's swizzled LDS strip (no barrier needed)
#pragma unroll
    for (int nf=0;nf<NF;nf++)
#pragma unroll
      for (int i=0;i<4;i++){
        int row = (lane>>4)*4 + i;
        int ch  = nf*2 + ((lane>>3)&1);
        Pl[Pbase + row*KVLEN + ((ch ^ (row&7)) << 3) + (lane&7)] = f2bf(sacc[nf][i]*sm[i]);
      }

    // O = P @ V  (both from swizzled LDS)
    floatx4 oacc[4] = {};
#pragma unroll
    for (int kk=0; kk<KVLEN/32; kk++){
      int prow = lane & 15;
      short8 pf = *(const short8*)&Pl[Pbase + prow*KVLEN + (((kk*4 + (lane>>4)) ^ (prow&7)) << 3)];
#pragma unroll
      for (int nd=0; nd<4; nd++){
        int d = nd*16 + (lane&15);
        short8 vf = *(const short8*)&Vt[d*KVLEN + (((kk*4 + (lane>>4)) ^ (d&7)) << 3)];
        oacc[nd] = __builtin_amdgcn_mfma_f32_16x16x32_bf16(pf, vf, oacc[nd], 0,0,0);
      }
    }

#pragma unroll
    for (int nd=0; nd<4; nd++)
#pragma unroll
      for (int i=0;i<4;i++){
        size_t row = qrow0 + sp*16 + (lane>>4)*4 + i;
        comb[row*1024 + oc + nd*16 + (lane&15)] = f2bf(oacc[nd][i]);
      }
  }
}

// ---------------- LayerNorm: bf16 h (32768x512) -> fp32 d_out ----------------
__global__ __launch_bounds__(256) void ln_kernel(const u16* __restrict__ hb,
    float* __restrict__ out, const float* __restrict__ g, const float* __restrict__ bta){
  int lane = threadIdx.x & 63, w = threadIdx.x >> 6;
  size_t row = (size_t)blockIdx.x*4 + w;
  const u16* p = hb + row*D_;
  short8 hv = *(const short8*)(p + lane*8);
  float f[8]; float s = 0.f, q = 0.f;
#pragma unroll
  for (int i=0;i<8;i++){ f[i] = bf2f((u16)hv[i]); s += f[i]; q += f[i]*f[i]; }
#pragma unroll
  for (int msk=1; msk<64; msk<<=1){ s += __shfl_xor(s, msk); q += __shfl_xor(q, msk); }
  float mean = s * (1.f/512.f);
  float var  = q * (1.f/512.f) - mean*mean;
  float inv  = rsqrtf(var + 1e-5f);
  float4 g0 = ((const float4*)g)[lane*2],   g1 = ((const float4*)g)[lane*2+1];
  float4 b0 = ((const float4*)bta)[lane*2], b1 = ((const float4*)bta)[lane*2+1];
  float4 o0, o1;
  o0.x = (f[0]-mean)*inv*g0.x + b0.x; o0.y = (f[1]-mean)*inv*g0.y + b0.y;
  o0.z = (f[2]-mean)*inv*g0.z + b0.z; o0.w = (f[3]-mean)*inv*g0.w + b0.w;
  o1.x = (f[4]-mean)*inv*g1.x + b1.x; o1.y = (f[5]-mean)*inv*g1.y + b1.y;
  o1.z = (f[6]-mean)*inv*g1.z + b1.z; o1.w = (f[7]-mean)*inv*g1.w + b1.w;
  float* op = out + row*D_;
  ((float4*)op)[lane*2]     = o0;
  ((float4*)op)[lane*2 + 1] = o1;
}

extern "C" void kernel_launch(void* const* d_in, const int* in_sizes, int n_in,
                              void* d_out, int out_size, void* d_ws, size_t ws_size,
                              hipStream_t stream)
{
  const float* x    = (const float*)d_in[0];
  const float* lq_w = (const float*)d_in[1];
  const float* lq_b = (const float*)d_in[2];
  const float* lk_w = (const float*)d_in[3];
  const float* lk_b = (const float*)d_in[4];
  const float* lv_w = (const float*)d_in[5];
  const float* lv_b = (const float*)d_in[6];
  const float* gq_w = (const float*)d_in[7];
  const float* gq_b = (const float*)d_in[8];
  const float* gk_w = (const float*)d_in[9];
  const float* gk_b = (const float*)d_in[10];
  const float* gv_w = (const float*)d_in[11];
  const float* gv_b = (const float*)d_in[12];
  const float* out_w = (const float*)d_in[13];
  const float* out_b = (const float*)d_in[14];
  const float* ln_g = (const float*)d_in[15];
  const float* ln_b = (const float*)d_in[16];

  char* ws = (char*)d_ws;
  size_t off = 0;
  auto alloc = [&](size_t bytes)->void*{ void* p = ws + off; off += (bytes + 255) & ~255ULL; return p; };
  u16*  xb    = (u16*) alloc((size_t)ROWS_*D_*2);        // 32768 x 512
  u16*  xg    = (u16*) alloc((size_t)512*512*2);         // 512 x 512
  u16*  WcatT = (u16*) alloc((size_t)2048*512*2);        // [lq|lk|lv|gq]^T
  u16*  WgT   = (u16*) alloc((size_t)1024*512*2);        // [gk|gv]^T
  u16*  WoutT = (u16*) alloc((size_t)512*1024*2);        // out_w^T
  float* bcat = (float*)alloc(2048*4);
  float* bg   = (float*)alloc(1024*4);
  u16*  qkvg  = (u16*) alloc((size_t)ROWS_*2048*2);      // 32768 x 2048
  u16*  gkv   = (u16*) alloc((size_t)512*1024*2);        // 512 x 1024
  u16*  comb  = (u16*) alloc((size_t)ROWS_*1024*2);      // 32768 x 1024
  // h (bf16) aliases qkvg (dead after attention; out-proj reads only comb+xb)
  u16*  hbuf  = qkvg;

  cast_x_kernel<<<16384,256,0,stream>>>(x, xb, xg, ROWS_*D_/4);
  transpose_cast6_kernel<<<dim3(8,8,6),256,0,stream>>>(lq_w, lk_w, lv_w, gq_w, gk_w, gv_w, WcatT, WgT);
  transpose_cast_kernel<<<dim3(8,16),256,0,stream>>>(out_w, WoutT, 1024, 512);
  build_bias_kernel<<<12,256,0,stream>>>(bcat, bg, lq_b, lk_b, lv_b, gq_b, gk_b, gv_b);

  // projections: qkvg = xb @ [lq|lk|lv|gq] + bias  (M=32768, N=2048, K=512)
  gemm_big<0><<<dim3(8,128),512,0,stream>>>(xb, WcatT, bcat, qkvg, nullptr, ROWS_, 2048, 512);
  // global k/v: gkv = xg @ [gk|gv] + bias
  gemm_small<<<dim3(8,4),256,0,stream>>>(xg, WgT, bg, gkv, 512, 1024, 512);

  attn_kernel<256,2048,false><<<dim3(8,32,4),512,0,stream>>>(qkvg, qkvg, comb);
  attn_kernel<128,1024,true ><<<dim3(8,32,4),512,0,stream>>>(qkvg, gkv,  comb);

  // out-proj + residual: hbuf = bf16(comb @ out_w + out_b + xb)
  gemm_big<1><<<dim3(2,128),512,0,stream>>>(comb, WoutT, out_b, hbuf, xb,
      ROWS_, 512, 1024);
  // LayerNorm: bf16 h -> fp32 d_out
  ln_kernel<<<8192,256,0,stream>>>(hbuf, (float*)d_out, ln_g, ln_b);
}

// Round 17
// 262.509 us; speedup vs baseline: 1.0551x; 1.0551x over previous
//
#include <hip/hip_runtime.h>
#include <hip/hip_bf16.h>
#include <stdint.h>

// HierarchicalAttention: B=4 S=8192 D=512 H=8 DK=64 LOCAL_W=256 STRIDE=64
// Baseline r16: 277us (gemm_big cross-region prefetch: 99.4us, kept).
// Dead ends: 7 GEMM schedules (24-28% MfmaUtil, structural); (512,4) GEMM
// bounds -> spills (r7); LN-fusion (r9); SEC-fold (r11); attn QBLK=128 (r14).
// This round: attn P-chunking (QBLK=256 kept, Pl 64->16KB => 80KB LDS,
// 2 blocks/CU) -- occupancy without r14's staging-ratio regression.
#define B_ 4
#define S_ 8192
#define D_ 512
#define H_ 8
#define DK_ 64
#define G_ 128
#define ROWS_ (B_*S_)   // 32768

typedef unsigned short u16;
typedef __attribute__((ext_vector_type(8))) short short8;   // 8 x bf16 (4 VGPR)
typedef __attribute__((ext_vector_type(4))) short short4v;  // 4 x bf16
typedef __attribute__((ext_vector_type(4))) float floatx4;

static __device__ __forceinline__ float bf2f(u16 u){
  union { uint32_t i; float f; } v; v.i = ((uint32_t)u) << 16; return v.f;
}
static __device__ __forceinline__ u16 f2bf(float f){
  union { float f; uint32_t i; } v; v.f = f;
  uint32_t u = v.i; u += 0x7fff + ((u >> 16) & 1); return (u16)(u >> 16);
}

// async global->LDS, 16B per lane. LDS dest must be wave-uniform base; HW
// writes lane l at ldsbase + l*16 (m104). Global src is per-lane.
static __device__ __forceinline__ void glds16(const u16* g, u16* l){
  __builtin_amdgcn_global_load_lds(
      (const __attribute__((address_space(1))) void*)g,
      (__attribute__((address_space(3))) void*)l, 16, 0, 0);
}

// ---------------- cast x (fp32 -> bf16) + gather global tokens ----------------
__global__ void cast_x_kernel(const float* __restrict__ x, u16* __restrict__ xb,
                              u16* __restrict__ xg, int n4){
  int i = blockIdx.x*blockDim.x + threadIdx.x;
  if (i >= n4) return;
  float4 v = ((const float4*)x)[i];
  short4v o;
  o[0] = (short)f2bf(v.x); o[1] = (short)f2bf(v.y);
  o[2] = (short)f2bf(v.z); o[3] = (short)f2bf(v.w);
  *(short4v*)(xb + (size_t)i*4) = o;
  int row = i >> 7;                      // token row (D=512, 4 elems/thread)
  if ((row & 63) == 0){                  // every 64th token -> xg
    int b = row >> 13, g = (row & 8191) >> 6;
    *(short4v*)(xg + ((size_t)(b*G_ + g)*D_) + (i & 127)*4) = o;
  }
}

// ---------------- transpose+cast weight: W (K x N) f32 -> Ot (N x K) bf16 ----------------
__global__ void transpose_cast_kernel(const float* __restrict__ W, u16* __restrict__ Ot, int K, int N){
  __shared__ float t[64][65];
  int n0 = blockIdx.x*64, k0 = blockIdx.y*64;
  int tx = threadIdx.x & 63, ty = threadIdx.x >> 6; // ty 0..3
#pragma unroll
  for (int j=0;j<16;j++){ int k = ty + j*4; t[k][tx] = W[(size_t)(k0+k)*N + n0+tx]; }
  __syncthreads();
#pragma unroll
  for (int j=0;j<16;j++){ int n = ty + j*4; Ot[(size_t)(n0+n)*K + k0 + tx] = f2bf(t[tx][n]); }
}

// six 512x512 transposes in one launch (z selects source)
__global__ void transpose_cast6_kernel(const float* s0, const float* s1, const float* s2,
    const float* s3, const float* s4, const float* s5,
    u16* __restrict__ WcatT, u16* __restrict__ WgT){
  __shared__ float t[64][65];
  int z = blockIdx.z;
  const float* W = (z==0)?s0:(z==1)?s1:(z==2)?s2:(z==3)?s3:(z==4)?s4:s5;
  u16* Ot = (z<4) ? (WcatT + (size_t)z*512*512) : (WgT + (size_t)(z-4)*512*512);
  int n0 = blockIdx.x*64, k0 = blockIdx.y*64;
  int tx = threadIdx.x & 63, ty = threadIdx.x >> 6;
#pragma unroll
  for (int j=0;j<16;j++){ int k = ty + j*4; t[k][tx] = W[(size_t)(k0+k)*512 + n0+tx]; }
  __syncthreads();
#pragma unroll
  for (int j=0;j<16;j++){ int n = ty + j*4; Ot[(size_t)(n0+n)*512 + k0 + tx] = f2bf(t[tx][n]); }
}

// ---------------- bias concat ----------------
__global__ void build_bias_kernel(float* __restrict__ bcat, float* __restrict__ bg,
    const float* lq_b, const float* lk_b, const float* lv_b, const float* gq_b,
    const float* gk_b, const float* gv_b){
  int i = blockIdx.x*blockDim.x + threadIdx.x;
  if (i < 2048){
    const float* s = (i < 512) ? lq_b : (i < 1024) ? lk_b : (i < 1536) ? lv_b : gq_b;
    bcat[i] = s[i & 511];
  } else if (i < 3072){
    int j = i - 2048;
    bg[j] = (j < 512) ? gk_b[j] : gv_b[j - 512];
  }
}

// ============ 256x256 BK=32, 4-deep ring, CROSS-REGION prefetch GEMM ============
// (r16: 99.4us, VGPR 124, best of 7 schedule variants.)
// MFMA(t) consumes frags read in region t-1; region t prefetches t+1's frags.
// Counted vmcnt(4): tile t+1 resident at barrier; t+2,t+3 DMA in flight.
// REQUIRES: T even, T >= 4. GRID MUST BE MULTIPLE OF 256 BLOCKS.
template<int EPI>
__global__ __launch_bounds__(512, 1) void gemm_big(
    const u16* __restrict__ A, const u16* __restrict__ Bt,
    const float* __restrict__ bias, u16* __restrict__ C,
    const u16* __restrict__ X, int M, int N, int K)
{
  __shared__ u16 SM[4][16384];   // 4 x 32KB: [A 16 frag-blocks | B 16 frag-blocks]
  const int tid = threadIdx.x, lane = tid & 63, w = tid >> 6;
  const int wm = w >> 2, wn = w & 3;          // 2M x 4N waves
  const int gx = gridDim.x;
  const int h = blockIdx.y * gx + blockIdx.x;
  const int chunk = (gx * gridDim.y) >> 3;
  const int work = (h & 7) * chunk + (h >> 3);   // XCD-aware bijective remap
  const int bx = work % gx, by = work / gx;
  const int m0 = by*256, n0 = bx*256;
  const int T = K >> 5;          // BK=32 tiles (even)

  const u16* gsrc[4]; int loff[4];
#pragma unroll
  for (int j = 0; j < 4; j++){
    int fb  = w*4 + j;
    int isB = fb >> 4;
    int blk = fb & 15;
    const u16* bp = isB ? Bt : A;
    int row = (isB ? n0 : m0) + blk*16 + (lane & 15);
    gsrc[j] = bp + (size_t)row * K + ((lane >> 4) * 8);
    loff[j] = fb*512;
  }

  floatx4 acc[8][4] = {};

  auto stageT = [&](int tt){
    u16* Sb_ = &SM[tt & 3][0];
#pragma unroll
    for (int j = 0; j < 4; j++) glds16(gsrc[j] + tt*32, Sb_ + loff[j]);
  };
  auto readFrags = [&](short8* Sa, short8* Sb, int slot){
    const u16* Tb = &SM[slot][0];
#pragma unroll
    for (int i=0;i<8;i++) Sa[i] = *(const short8*)(Tb + (wm*8 + i)*512 + lane*8);
#pragma unroll
    for (int j=0;j<4;j++) Sb[j] = *(const short8*)(Tb + (16 + wn*4 + j)*512 + lane*8);
  };
  auto doMfma = [&](const short8* Sa, const short8* Sb){
#pragma unroll
    for (int i=0;i<8;i++)
#pragma unroll
      for (int j=0;j<4;j++)
        acc[i][j] = __builtin_amdgcn_mfma_f32_16x16x32_bf16(Sa[i], Sb[j], acc[i][j], 0,0,0);
  };

  short8 A0[8], B0[4], A1[8], B1[4];

  stageT(0); stageT(1); stageT(2);
  asm volatile("s_waitcnt vmcnt(8)" ::: "memory");   // tile 0 resident
  __builtin_amdgcn_s_barrier();
  readFrags(A0, B0, 0);

  for (int t = 0; t < T; t += 2){
    if (t + 2 < T) asm volatile("s_waitcnt vmcnt(4)" ::: "memory");  // t+1 resident
    else           asm volatile("s_waitcnt vmcnt(0)" ::: "memory");
    __builtin_amdgcn_s_barrier();
    if (t + 3 < T) stageT(t + 3);
    readFrags(A1, B1, (t + 1) & 3);
    doMfma(A0, B0);

    if (t + 3 < T) asm volatile("s_waitcnt vmcnt(4)" ::: "memory");  // t+2 resident
    else           asm volatile("s_waitcnt vmcnt(0)" ::: "memory");
    __builtin_amdgcn_s_barrier();
    if (t + 4 < T) stageT(t + 4);
    if (t + 2 < T) readFrags(A0, B0, (t + 2) & 3);
    doMfma(A1, B1);
  }

#pragma unroll
  for (int mi=0; mi<8; mi++)
#pragma unroll
    for (int nj=0; nj<4; nj++){
      int col = n0 + (wn*4 + nj)*16 + (lane & 15);
      float bv = bias[col];
#pragma unroll
      for (int ii=0; ii<4; ii++){
        size_t row = (size_t)(m0 + (wm*8 + mi)*16 + (lane>>4)*4 + ii);
        float v = acc[mi][nj][ii] + bv;
        if (EPI == 1) v += bf2f(X[row*N + col]);
        C[row*N + col] = f2bf(v);
      }
    }
}

// ---------------- small 128^2 GEMM (for 512x1024x512 gkv) ----------------
__global__ __launch_bounds__(256) void gemm_small(
    const u16* __restrict__ A, const u16* __restrict__ Bt,
    const float* __restrict__ bias, u16* __restrict__ C,
    int M, int N, int K)
{
  __shared__ u16 As[128*32];
  __shared__ u16 Bs[128*32];
  const int tid = threadIdx.x, lane = tid & 63, w = tid >> 6;
  const int m0 = blockIdx.y*128, n0 = blockIdx.x*128;
  const int wm = (w>>1)*64, wn = (w&1)*64;
  floatx4 acc[4][4] = {};
  const int c0 = 2*w;
  const int sr = lane >> 2;
  const int sc = (lane & 3) * 8;
  const u16* ga0 = A  + (size_t)(m0 +  c0     *16 + sr)*K + sc;
  const u16* ga1 = A  + (size_t)(m0 + (c0 + 1)*16 + sr)*K + sc;
  const u16* gb0 = Bt + (size_t)(n0 +  c0     *16 + sr)*K + sc;
  const u16* gb1 = Bt + (size_t)(n0 + (c0 + 1)*16 + sr)*K + sc;
  u16* la0 = &As[ c0     *512];
  u16* la1 = &As[(c0 + 1)*512];
  u16* lb0 = &Bs[ c0     *512];
  u16* lb1 = &Bs[(c0 + 1)*512];

  for (int k0 = 0; k0 < K; k0 += 32){
    __syncthreads();
    glds16(ga0 + k0, la0);
    glds16(ga1 + k0, la1);
    glds16(gb0 + k0, lb0);
    glds16(gb1 + k0, lb1);
    __syncthreads();
    short8 af[4], bf[4];
#pragma unroll
    for (int i=0;i<4;i++) af[i] = *(const short8*)&As[(wm + i*16 + (lane&15))*32 + (lane>>4)*8];
#pragma unroll
    for (int i=0;i<4;i++) bf[i] = *(const short8*)&Bs[(wn + i*16 + (lane&15))*32 + (lane>>4)*8];
#pragma unroll
    for (int mi=0;mi<4;mi++)
#pragma unroll
      for (int ni=0;ni<4;ni++)
        acc[mi][ni] = __builtin_amdgcn_mfma_f32_16x16x32_bf16(af[mi], bf[ni], acc[mi][ni], 0,0,0);
  }

#pragma unroll
  for (int mi=0;mi<4;mi++)
#pragma unroll
    for (int ni=0;ni<4;ni++){
      int col = n0 + wn + ni*16 + (lane&15);
      float bv = bias[col];
#pragma unroll
      for (int i=0;i<4;i++){
        size_t row = (size_t)(m0 + wm + mi*16 + (lane>>4)*4 + i);
        C[row*N + col] = f2bf(acc[mi][ni][i] + bv);
      }
    }
}

// ================= attention v5: P-chunked, 2 blocks/CU =================
// 512 threads (8 waves), per block: one (b, window, head): 256 q-rows.
// K staged ONCE (glds16, pre-swizzled source); V transposed once (all-thread
// 4x8 in-reg transpose). P phase runs in KV-chunks of 64: per chunk, QK^T
// (4 frags) -> exp -> per-wave P[16][64] strip -> 2 PV k-steps; O and sum
// accumulate across chunks (exact: no-max softmax has no rescale).
// LDS: KVLEN*64 (K) + 64*KVLEN (Vt) + 8*16*64 (P) u16:
//   local KVLEN=256: 80KB -> 2 blocks/CU; global KVLEN=128: 48KB -> 3/CU.
// launch_bounds(512,4): caps VGPR at 128 (attn footprint ~90; fits).
// Strip loop is barrier-free (per-wave P; K/V read-only after stage).
template<int KVLEN, int KSTRIDE, bool GLOBAL>
__global__ __launch_bounds__(512, 4) void attn_kernel(
    const u16* __restrict__ qkv, const u16* __restrict__ kvbuf, u16* __restrict__ comb)
{
  __shared__ u16 SM[KVLEN*128 + 8192];
  u16* Kl = SM;                       // [KVLEN][64] swizzled chunks
  u16* Vt = SM + KVLEN*64;            // [64][KVLEN] swizzled chunks
  u16* Pl = SM + KVLEN*128;           // [8 waves][16][64] swizzled chunks
  const int tid = threadIdx.x, lane = tid & 63, w = tid >> 6;
  const int h = blockIdx.x, n = blockIdx.y, b = blockIdx.z;
  const size_t qrow0 = (size_t)b*S_ + (size_t)n*256;
  const int krow0 = GLOBAL ? b*G_ : (b*S_ + n*256);
  const int qc = (GLOBAL ? 1536 : 0)   + h*DK_;
  const int kc = (GLOBAL ? 0    : 512) + h*DK_;
  const int vc = (GLOBAL ? 512  : 1024)+ h*DK_;
  const int oc = (GLOBAL ? 512  : 0)   + h*DK_;
  constexpr int NC = KVLEN/64;        // kv chunks

  // ---- stage K: wave w covers rows [w*KVLEN/8, +KVLEN/8) ----
  {
    const int rpw = KVLEN/8;
    const int r0w = w * rpw;
    const int cg = ((lane & 7) ^ (lane >> 3)) * 8;   // pre-swizzled source chunk
    const int rl = lane >> 3;
#pragma unroll
    for (int j = 0; j < rpw; j += 8){
      int row = r0w + j + rl;
      glds16(kvbuf + (size_t)(krow0 + row)*KSTRIDE + kc + cg, &Kl[(r0w + j)*64]);
    }
  }
  // ---- stage Vt: (KVLEN/4)*8 tasks over ALL threads; 4x8 in-reg transpose ----
  if (tid < (KVLEN/4)*8){
    const int rb = tid >> 3;             // 4-row kv block
    const int kv0 = rb * 4;
    const int d0 = (tid & 7) * 8;
    const u16* vp = kvbuf + (size_t)(krow0 + kv0)*KSTRIDE + vc + d0;
    short8 rIn[4];
#pragma unroll
    for (int i=0;i<4;i++) rIn[i] = *(const short8*)(vp + (size_t)i*KSTRIDE);
    const int c   = rb >> 1;             // kv chunk (8 elems)
    const int sub = kv0 & 7;             // 0 or 4 within chunk
#pragma unroll
    for (int dd=0; dd<8; dd++){
      int d = d0 + dd;
      short4v o;
#pragma unroll
      for (int j=0;j<4;j++) o[j] = rIn[j][dd];
      *(short4v*)&Vt[d*KVLEN + ((c ^ (d&7)) << 3) + sub] = o;
    }
  }
  __syncthreads();

  const float sc2 = 0.125f * 1.44269504f;   // scale * log2(e), for exp2
  const int Pbase = w*16*64;

  for (int sp = 2*w; sp < 2*w + 2; sp++){
    const u16* qp = qkv + (qrow0 + sp*16 + (lane&15))*2048 + qc + ((lane>>4)*8);
    short8 qf0 = *(const short8*)qp;
    short8 qf1 = *(const short8*)(qp + 32);

    floatx4 oacc[4] = {};
    float sm[4] = {0.f,0.f,0.f,0.f};

#pragma unroll
    for (int c = 0; c < NC; c++){
      // ---- S = Q K^T for this 64-kv chunk ----
      floatx4 sacc[4];
#pragma unroll
      for (int nf = 0; nf < 4; nf++){
        const u16* kb = &Kl[((c*4 + nf)*16 + (lane&15))*64];
        short8 kf0 = *(const short8*)(kb + ((( lane>>4)      ^ (lane&7)) << 3));
        short8 kf1 = *(const short8*)(kb + ((((lane>>4) + 4) ^ (lane&7)) << 3));
        floatx4 z = {0.f,0.f,0.f,0.f};
        z = __builtin_amdgcn_mfma_f32_16x16x32_bf16(qf0, kf0, z, 0,0,0);
        z = __builtin_amdgcn_mfma_f32_16x16x32_bf16(qf1, kf1, z, 0,0,0);
        sacc[nf] = z;
      }
      // ---- exp (no max-shift), accumulate sums, write UNNORMALIZED P chunk ----
#pragma unroll
      for (int nf=0;nf<4;nf++)
#pragma unroll
        for (int i=0;i<4;i++){
          float e = exp2f(sacc[nf][i] * sc2);
          sm[i] += e;
          int row = (lane>>4)*4 + i;
          int ch  = nf*2 + ((lane>>3)&1);
          Pl[Pbase + row*64 + ((ch ^ (row&7)) << 3) + (lane&7)] = f2bf(e);
        }
      // ---- O += P @ V for this chunk ----
#pragma unroll
      for (int kk=0; kk<2; kk++){
        int prow = lane & 15;
        short8 pf = *(const short8*)&Pl[Pbase + prow*64 + (((kk*4 + (lane>>4)) ^ (prow&7)) << 3)];
#pragma unroll
        for (int nd=0; nd<4; nd++){
          int d = nd*16 + (lane&15);
          short8 vf = *(const short8*)&Vt[d*KVLEN + (((c*8 + kk*4 + (lane>>4)) ^ (d&7)) << 3)];
          oacc[nd] = __builtin_amdgcn_mfma_f32_16x16x32_bf16(pf, vf, oacc[nd], 0,0,0);
        }
      }
    }

    // ---- finalize strip: reduce sums over 16 kv lanes, normalize, store ----
#pragma unroll
    for (int i=0;i<4;i++){
#pragma unroll
      for (int msk=1; msk<16; msk<<=1) sm[i] += __shfl_xor(sm[i], msk);
      sm[i] = 1.f / sm[i];
    }
#pragma unroll
    for (int nd=0; nd<4; nd++)
#pragma unroll
      for (int i=0;i<4;i++){
        size_t row = qrow0 + sp*16 + (lane>>4)*4 + i;
        comb[row*1024 + oc + nd*16 + (lane&15)] = f2bf(oacc[nd][i] * sm[i]);
      }
  }
}

// ---------------- LayerNorm: bf16 h (32768x512) -> fp32 d_out ----------------
__global__ __launch_bounds__(256) void ln_kernel(const u16* __restrict__ hb,
    float* __restrict__ out, const float* __restrict__ g, const float* __restrict__ bta){
  int lane = threadIdx.x & 63, w = threadIdx.x >> 6;
  size_t row = (size_t)blockIdx.x*4 + w;
  const u16* p = hb + row*D_;
  short8 hv = *(const short8*)(p + lane*8);
  float f[8]; float s = 0.f, q = 0.f;
#pragma unroll
  for (int i=0;i<8;i++){ f[i] = bf2f((u16)hv[i]); s += f[i]; q += f[i]*f[i]; }
#pragma unroll
  for (int msk=1; msk<64; msk<<=1){ s += __shfl_xor(s, msk); q += __shfl_xor(q, msk); }
  float mean = s * (1.f/512.f);
  float var  = q * (1.f/512.f) - mean*mean;
  float inv  = rsqrtf(var + 1e-5f);
  float4 g0 = ((const float4*)g)[lane*2],   g1 = ((const float4*)g)[lane*2+1];
  float4 b0 = ((const float4*)bta)[lane*2], b1 = ((const float4*)bta)[lane*2+1];
  float4 o0, o1;
  o0.x = (f[0]-mean)*inv*g0.x + b0.x; o0.y = (f[1]-mean)*inv*g0.y + b0.y;
  o0.z = (f[2]-mean)*inv*g0.z + b0.z; o0.w = (f[3]-mean)*inv*g0.w + b0.w;
  o1.x = (f[4]-mean)*inv*g1.x + b1.x; o1.y = (f[5]-mean)*inv*g1.y + b1.y;
  o1.z = (f[6]-mean)*inv*g1.z + b1.z; o1.w = (f[7]-mean)*inv*g1.w + b1.w;
  float* op = out + row*D_;
  ((float4*)op)[lane*2]     = o0;
  ((float4*)op)[lane*2 + 1] = o1;
}

extern "C" void kernel_launch(void* const* d_in, const int* in_sizes, int n_in,
                              void* d_out, int out_size, void* d_ws, size_t ws_size,
                              hipStream_t stream)
{
  const float* x    = (const float*)d_in[0];
  const float* lq_w = (const float*)d_in[1];
  const float* lq_b = (const float*)d_in[2];
  const float* lk_w = (const float*)d_in[3];
  const float* lk_b = (const float*)d_in[4];
  const float* lv_w = (const float*)d_in[5];
  const float* lv_b = (const float*)d_in[6];
  const float* gq_w = (const float*)d_in[7];
  const float* gq_b = (const float*)d_in[8];
  const float* gk_w = (const float*)d_in[9];
  const float* gk_b = (const float*)d_in[10];
  const float* gv_w = (const float*)d_in[11];
  const float* gv_b = (const float*)d_in[12];
  const float* out_w = (const float*)d_in[13];
  const float* out_b = (const float*)d_in[14];
  const float* ln_g = (const float*)d_in[15];
  const float* ln_b = (const float*)d_in[16];

  char* ws = (char*)d_ws;
  size_t off = 0;
  auto alloc = [&](size_t bytes)->void*{ void* p = ws + off; off += (bytes + 255) & ~255ULL; return p; };
  u16*  xb    = (u16*) alloc((size_t)ROWS_*D_*2);        // 32768 x 512
  u16*  xg    = (u16*) alloc((size_t)512*512*2);         // 512 x 512
  u16*  WcatT = (u16*) alloc((size_t)2048*512*2);        // [lq|lk|lv|gq]^T
  u16*  WgT   = (u16*) alloc((size_t)1024*512*2);        // [gk|gv]^T
  u16*  WoutT = (u16*) alloc((size_t)512*1024*2);        // out_w^T
  float* bcat = (float*)alloc(2048*4);
  float* bg   = (float*)alloc(1024*4);
  u16*  qkvg  = (u16*) alloc((size_t)ROWS_*2048*2);      // 32768 x 2048
  u16*  gkv   = (u16*) alloc((size_t)512*1024*2);        // 512 x 1024
  u16*  comb  = (u16*) alloc((size_t)ROWS_*1024*2);      // 32768 x 1024
  // h (bf16) aliases qkvg (dead after attention; out-proj reads only comb+xb)
  u16*  hbuf  = qkvg;

  cast_x_kernel<<<16384,256,0,stream>>>(x, xb, xg, ROWS_*D_/4);
  transpose_cast6_kernel<<<dim3(8,8,6),256,0,stream>>>(lq_w, lk_w, lv_w, gq_w, gk_w, gv_w, WcatT, WgT);
  transpose_cast_kernel<<<dim3(8,16),256,0,stream>>>(out_w, WoutT, 1024, 512);
  build_bias_kernel<<<12,256,0,stream>>>(bcat, bg, lq_b, lk_b, lv_b, gq_b, gk_b, gv_b);

  // projections: qkvg = xb @ [lq|lk|lv|gq] + bias  (M=32768, N=2048, K=512)
  gemm_big<0><<<dim3(8,128),512,0,stream>>>(xb, WcatT, bcat, qkvg, nullptr, ROWS_, 2048, 512);
  // global k/v: gkv = xg @ [gk|gv] + bias
  gemm_small<<<dim3(8,4),256,0,stream>>>(xg, WgT, bg, gkv, 512, 1024, 512);

  attn_kernel<256,2048,false><<<dim3(8,32,4),512,0,stream>>>(qkvg, qkvg, comb);
  attn_kernel<128,1024,true ><<<dim3(8,32,4),512,0,stream>>>(qkvg, gkv,  comb);

  // out-proj + residual: hbuf = bf16(comb @ out_w + out_b + xb)
  gemm_big<1><<<dim3(2,128),512,0,stream>>>(comb, WoutT, out_b, hbuf, xb,
      ROWS_, 512, 1024);
  // LayerNorm: bf16 h -> fp32 d_out
  ln_kernel<<<8192,256,0,stream>>>(hbuf, (float*)d_out, ln_g, ln_b);
}